// Round 14
// baseline (114.524 us; speedup 1.0000x reference)
//
#include <hip/hip_runtime.h>
#include <hip/hip_bf16.h>

// Problem constants
#define BB   8192      // batch
#define DD   2048      // embed dim
#define KK   512       // num directions
#define TT   17        // quadrature points

// GEMM tile: 128x128x128, 256 blocks (1/CU), 2-phase proven sync, NT=16.
#define BM   128
#define BN   128
#define BK   128
#define NT   (DD / BK)   // 16 K-steps

#define NZB  1024        // prep_z row-split blocks (8 rows each)

typedef __attribute__((ext_vector_type(8))) short  bf16x8;
typedef __attribute__((ext_vector_type(4))) float  f32x4;

__device__ __forceinline__ void gload16(const void* g, void* l) {
  __builtin_amdgcn_global_load_lds(
      (const __attribute__((address_space(1))) void*)g,
      (__attribute__((address_space(3))) void*)l,
      16, 0, 0);
}

// ---------- prep z: bf16 conversion + NON-ATOMIC per-block col partials -------
// 1024 blocks x 8 rows; thread owns 8 contiguous cols; 4-row load batches.
__global__ __launch_bounds__(256) void prep_z_kernel(
    const float* __restrict__ z, unsigned short* __restrict__ zb,
    float* __restrict__ part2) {
  int c = threadIdx.x * 8;              // 0..2040
  int r0 = blockIdx.x * 8;
  float s[8] = {0,0,0,0,0,0,0,0}, ss[8] = {0,0,0,0,0,0,0,0};
  for (int ch = 0; ch < 2; ++ch) {
    float4 u[4][2];
    #pragma unroll
    for (int rr = 0; rr < 4; ++rr) {
      const float* p = &z[(size_t)(r0 + ch * 4 + rr) * DD + c];
      u[rr][0] = *(const float4*)p;
      u[rr][1] = *(const float4*)(p + 4);
    }
    #pragma unroll
    for (int rr = 0; rr < 4; ++rr) {
      float f[8] = {u[rr][0].x, u[rr][0].y, u[rr][0].z, u[rr][0].w,
                    u[rr][1].x, u[rr][1].y, u[rr][1].z, u[rr][1].w};
      bf16x8 o;
      #pragma unroll
      for (int i = 0; i < 8; ++i) {
        s[i] += f[i]; ss[i] += f[i] * f[i];
        __hip_bfloat16 h = __float2bfloat16(f[i]);
        o[i] = *(short*)&h;
      }
      *(bf16x8*)&zb[(size_t)(r0 + ch * 4 + rr) * DD + c] = o;
    }
  }
  float* pb = part2 + (size_t)blockIdx.x * 4096;
  *(float4*)&pb[c]        = (float4){s[0], s[1], s[2], s[3]};
  *(float4*)&pb[c + 4]    = (float4){s[4], s[5], s[6], s[7]};
  *(float4*)&pb[2048 + c]     = (float4){ss[0], ss[1], ss[2], ss[3]};
  *(float4*)&pb[2048 + c + 4] = (float4){ss[4], ss[5], ss[6], ss[7]};
}

// ---------- merged fold, properly parallel ------------------------------------
// blocks 0..511: z-partial fold (64 d-groups x 8 b-eighths, 32 loads/thread)
// blocks 512..543: dir sumsq (32 row-groups, float4 coalesced, 32 loads/thread)
__global__ __launch_bounds__(256) void reduce2_kernel(
    const float* __restrict__ part2, float* __restrict__ part5,
    const float* __restrict__ dir, float* __restrict__ part3) {
  int bid = blockIdx.x;
  int tid = threadIdx.x;
  if (bid < 512) {
    int dgrp = bid & 63, bq = bid >> 6;      // d-group 0..63, b-eighth 0..7
    int d = dgrp * 64 + (tid & 63);          // 0..4095 (sum|sumsq columns)
    int ch = tid >> 6;                       // 0..3
    int b0 = bq * 128 + ch * 32;
    float s = 0.f;
    for (int b = b0; b < b0 + 32; ++b)
      s += part2[(size_t)b * 4096 + d];
    __shared__ float rs[4][64];
    rs[ch][tid & 63] = s;
    __syncthreads();
    if (tid < 64)
      part5[(size_t)bq * 4096 + dgrp * 64 + tid] =
          rs[0][tid] + rs[1][tid] + rs[2][tid] + rs[3][tid];
  } else {
    int rg = bid - 512;                      // 0..31, rows [rg*64, +64)
    int c4 = tid & 127;                      // float4 column (512 cols / 4)
    int half = tid >> 7;                     // 0/1 row parity
    int r0 = rg * 64 + half;
    float4 q = {0.f, 0.f, 0.f, 0.f};
    #pragma unroll 8
    for (int i = 0; i < 32; ++i) {
      float4 v = *(const float4*)&dir[(size_t)(r0 + 2 * i) * KK + c4 * 4];
      q.x += v.x * v.x; q.y += v.y * v.y; q.z += v.z * v.z; q.w += v.w * v.w;
    }
    __shared__ float rd[2][512];
    *(float4*)&rd[half][c4 * 4] = q;
    __syncthreads();
    if (tid < 128) {
      float4 a = *(float4*)&rd[0][tid * 4];
      float4 b = *(float4*)&rd[1][tid * 4];
      float4 o = {a.x + b.x, a.y + b.y, a.z + b.z, a.w + b.w};
      *(float4*)&part3[(size_t)rg * KK + tid * 4] = o;
    }
  }
}

// ---------- finalize 1: fold part5/part3 -> invnorm + var_floor + zero psum ---
__global__ __launch_bounds__(256) void finalize1_kernel(
    const float* __restrict__ part5, const float* __restrict__ part3,
    float* __restrict__ invnorm, float* __restrict__ out,
    float* __restrict__ psum) {
  int tid = threadIdx.x;
  // zero psum+psumsq (contiguous 2*KK floats) before gemm's atomics
  for (int i = tid; i < 2 * KK; i += 256) psum[i] = 0.f;
  for (int k = tid; k < KK; k += 256) {
    float ssq = 0.f;
    #pragma unroll
    for (int i = 0; i < 32; ++i) ssq += part3[(size_t)i * KK + k];
    float n = sqrtf(ssq);
    invnorm[k] = 1.0f / fmaxf(n, 1e-12f);
  }
  float acc = 0.f;
  for (int d = tid; d < DD; d += 256) {
    float s = 0.f, ss = 0.f;
    #pragma unroll
    for (int i = 0; i < 8; ++i) {
      s  += part5[i * 4096 + d];
      ss += part5[i * 4096 + 2048 + d];
    }
    float var = (ss - s * s / (float)BB) / (float)(BB - 1);
    float sd = sqrtf(fmaxf(var, 0.f));
    acc += fmaxf(1.0f - sd, 0.0f);
  }
  __shared__ float red[256];
  red[tid] = acc; __syncthreads();
  for (int s = 128; s > 0; s >>= 1) {
    if (tid < s) red[tid] += red[tid + s];
    __syncthreads();
  }
  if (tid == 0) out[0] = red[0] / (float)DD;   // ecf_final atomically adds the rest
}

// ---------- dirT: normalize + bf16 + transpose (D,K)->(K,D) -------------------
__global__ __launch_bounds__(256) void dirT_kernel(
    const float* __restrict__ dir, const float* __restrict__ invnorm,
    unsigned short* __restrict__ dT) {
  __shared__ unsigned short tile[64][65];   // +1 pad
  int n0 = blockIdx.x * 64;   // K dim (8 blocks)
  int d0 = blockIdx.y * 64;   // D dim (32 blocks)
  int tx = threadIdx.x & 63, ty = threadIdx.x >> 6;
  float inv = invnorm[n0 + tx];
  #pragma unroll
  for (int i = 0; i < 16; ++i) {
    int dr = ty + i * 4;
    float v = dir[(size_t)(d0 + dr) * KK + n0 + tx] * inv;
    __hip_bfloat16 h = __float2bfloat16(v);
    tile[dr][tx] = *(unsigned short*)&h;
  }
  __syncthreads();
  #pragma unroll
  for (int i = 0; i < 16; ++i) {
    int nr = ty + i * 4;
    dT[(size_t)(n0 + nr) * DD + d0 + tx] = tile[tx][nr];
  }
}

// ---------- bf16 MFMA GEMM: proj(B,K) = zb(B,D) @ dT(K,D)^T -------------------
// 256 blocks (1/CU), 4 waves (2m x 2n), wave tile 64x64 (4x4 acc), BK=128.
// Proven 2-phase sync: STAGE(next) at loop top; reads+MFMA; vmcnt(0)+barrier.
// LDS 128KB dbuf; T2 XOR-swizzle: LDS[row][g] = Global[row][g ^ (row&7)].
__global__ __launch_bounds__(256) void gemm_bf16_kernel(
    const unsigned short* __restrict__ zb, const unsigned short* __restrict__ dT,
    float* __restrict__ proj, float* __restrict__ psum, float* __restrict__ psumsq) {
  __shared__ __align__(16) short As[2][BM * BK];   // 32KB/buf
  __shared__ __align__(16) short Bs[2][BN * BK];   // 32KB/buf

  int tid = threadIdx.x;
  int w = tid >> 6, l = tid & 63;

  // XCD-chunked swizzle (bijective): XCD x owns m-blocks [x*8, x*8+8)
  int bid = blockIdx.x;               // 0..255
  int xcd = bid & 7, slot = bid >> 3; // slot 0..31
  int bmi = xcd * 8 + (slot >> 2);    // 0..63
  int bni = slot & 3;                 // 0..3
  int bm = bmi * BM, bn = bni * BN;

  // Staging: one gload16 covers 4 rows x 16 granules (lane->row l>>4, gran l&15).
  int r4 = l >> 4;                     // row within 4-row gload (0..3)
  int gsw_e = ((l & 15) ^ r4) * 8;     // even strip: row&7 = r4
  int gsw_o = ((l & 15) ^ (r4 + 4)) * 8; // odd strip: row&7 = r4+4
  const unsigned short* aRow = zb + (size_t)(bm + w * 32 + r4) * DD;
  const unsigned short* bRow = dT + (size_t)(bn + w * 32 + r4) * DD;

#define STAGE(buf, kt) do {                                                   \
    const unsigned short* a_ = aRow + (size_t)(kt) * BK;                      \
    const unsigned short* b_ = bRow + (size_t)(kt) * BK;                      \
    gload16(a_ + 0 * 4 * DD + gsw_e, &As[buf][(w * 32 + 0) * BK]);            \
    gload16(b_ + 0 * 4 * DD + gsw_e, &Bs[buf][(w * 32 + 0) * BK]);            \
    gload16(a_ + 1 * 4 * DD + gsw_o, &As[buf][(w * 32 + 4) * BK]);            \
    gload16(b_ + 1 * 4 * DD + gsw_o, &Bs[buf][(w * 32 + 4) * BK]);            \
    gload16(a_ + 2 * 4 * DD + gsw_e, &As[buf][(w * 32 + 8) * BK]);            \
    gload16(b_ + 2 * 4 * DD + gsw_e, &Bs[buf][(w * 32 + 8) * BK]);            \
    gload16(a_ + 3 * 4 * DD + gsw_o, &As[buf][(w * 32 + 12) * BK]);           \
    gload16(b_ + 3 * 4 * DD + gsw_o, &Bs[buf][(w * 32 + 12) * BK]);           \
    gload16(a_ + 4 * 4 * DD + gsw_e, &As[buf][(w * 32 + 16) * BK]);           \
    gload16(b_ + 4 * 4 * DD + gsw_e, &Bs[buf][(w * 32 + 16) * BK]);           \
    gload16(a_ + 5 * 4 * DD + gsw_o, &As[buf][(w * 32 + 20) * BK]);           \
    gload16(b_ + 5 * 4 * DD + gsw_o, &Bs[buf][(w * 32 + 20) * BK]);           \
    gload16(a_ + 6 * 4 * DD + gsw_e, &As[buf][(w * 32 + 24) * BK]);           \
    gload16(b_ + 6 * 4 * DD + gsw_e, &Bs[buf][(w * 32 + 24) * BK]);           \
    gload16(a_ + 7 * 4 * DD + gsw_o, &As[buf][(w * 32 + 28) * BK]);           \
    gload16(b_ + 7 * 4 * DD + gsw_o, &Bs[buf][(w * 32 + 28) * BK]);           \
  } while (0)

  int wm = (w >> 1) * 64, wn = (w & 1) * 64;
  int fr = l & 15, fq = l >> 4;
  int fx = fr & 7;                     // = (LDS row)&7 for all fragment rows

  f32x4 acc[4][4];
  f32x4 zero4 = {0.f, 0.f, 0.f, 0.f};
  #pragma unroll
  for (int mi = 0; mi < 4; ++mi)
    #pragma unroll
    for (int ni = 0; ni < 4; ++ni) acc[mi][ni] = zero4;

  STAGE(0, 0);
  asm volatile("s_waitcnt vmcnt(0)" ::: "memory");
  __builtin_amdgcn_s_barrier();

  for (int t = 0; t < NT; ++t) {
    int cur = t & 1;
    if (t + 1 < NT) STAGE(cur ^ 1, t + 1);   // issue next-tile loads first
    #pragma unroll
    for (int kk = 0; kk < 4; ++kk) {
      bf16x8 av[4], bv[4];
      int go = ((kk * 4 + fq) ^ fx) * 8;     // swizzled 16B-granule read
      #pragma unroll
      for (int mi = 0; mi < 4; ++mi)
        av[mi] = *(const bf16x8*)&As[cur][(wm + mi * 16 + fr) * BK + go];
      #pragma unroll
      for (int ni = 0; ni < 4; ++ni)
        bv[ni] = *(const bf16x8*)&Bs[cur][(wn + ni * 16 + fr) * BK + go];
      #pragma unroll
      for (int mi = 0; mi < 4; ++mi)
        #pragma unroll
        for (int ni = 0; ni < 4; ++ni)
          acc[mi][ni] = __builtin_amdgcn_mfma_f32_16x16x32_bf16(av[mi], bv[ni], acc[mi][ni], 0, 0, 0);
    }
    asm volatile("s_waitcnt vmcnt(0)" ::: "memory");   // next tile staged
    __builtin_amdgcn_s_barrier();                      // + all reads of cur done
  }
#undef STAGE

  // Epilogue: write proj + fused column stats (sum, sumsq over wave's 64 rows)
  #pragma unroll
  for (int ni = 0; ni < 4; ++ni) {
    float s = 0.f, q = 0.f;
    int col = bn + wn + ni * 16 + fr;
    #pragma unroll
    for (int mi = 0; mi < 4; ++mi)
      #pragma unroll
      for (int j = 0; j < 4; ++j) {
        float v = acc[mi][ni][j];
        s += v; q += v * v;
        proj[(size_t)(bm + wm + mi * 16 + fq * 4 + j) * KK + col] = v;
      }
    s += __shfl_xor(s, 16); q += __shfl_xor(q, 16);
    s += __shfl_xor(s, 32); q += __shfl_xor(q, 32);
    if (fq == 0) {
      atomicAdd(&psum[col], s);
      atomicAdd(&psumsq[col], q);
    }
  }
}

// ---------- ECF: block (kx,ry) covers 64 k-cols x 64 rows ---------------------
// 1024 blocks (4/CU). Inline finalize2: mu/invsig derived from psum/psumsq.
__global__ __launch_bounds__(256) void ecf_kernel(
    const float* __restrict__ proj, const float* __restrict__ psum,
    const float* __restrict__ psumsq, float* __restrict__ part) {
  int kx = blockIdx.x, ry = blockIdx.y;
  int tid = threadIdx.x;
  int kl = tid & 63, w = tid >> 6;
  int k = kx * 64 + kl;
  float sk = psum[k], qk = psumsq[k];
  float m = sk / (float)BB;
  float var = (qk - sk * sk / (float)BB) / (float)(BB - 1);
  float sd = sqrtf(fmaxf(var, 0.f));
  float is = 1.0f / (sd + 1e-8f);
  int r0 = ry * 64 + w * 16;
  const float dt = 2.0f / 17.0f;

  float ac[TT], as[TT];
  #pragma unroll
  for (int j = 0; j < TT; ++j) { ac[j] = 0.f; as[j] = 0.f; }

  #pragma unroll 4
  for (int i = 0; i < 16; ++i) {
    float p = (proj[(size_t)(r0 + i) * KK + k] - m) * is;
    float th = dt * p;
    float s1, c1;
    __sincosf(th, &s1, &c1);
    float tc = 2.0f * c1;
    float cj = c1, sj = s1, cjm = 1.0f, sjm = 0.0f;
    ac[0] += c1; as[0] += s1;
    #pragma unroll
    for (int j = 1; j < TT; ++j) {
      float cn = tc * cj - cjm;
      float sn = tc * sj - sjm;
      cjm = cj; sjm = sj; cj = cn; sj = sn;
      ac[j] += cj; as[j] += sj;
    }
  }

  __shared__ float red[4 * 2176];     // [wave][kl*34 + jj]
  int base = w * 2176 + kl * 34;
  #pragma unroll
  for (int j = 0; j < TT; ++j) {
    red[base + j] = ac[j];
    red[base + 17 + j] = as[j];
  }
  __syncthreads();
  for (int idx = tid; idx < 2176; idx += 256) {
    float v = red[idx] + red[2176 + idx] + red[4352 + idx] + red[6528 + idx];
    part[(size_t)(ry * 8 + kx) * 2176 + idx] = v;
  }
}

// ---------- reduce partials -> integrand -> atomic add into out ---------------
__global__ __launch_bounds__(256) void ecf_final_kernel(
    const float* __restrict__ part, float* __restrict__ out) {
  int gi = blockIdx.x * 256 + threadIdx.x;   // 0..8703 = 512k x 17j
  int kx = gi / 1088;                        // 1088 = 64*17
  int r2 = gi - kx * 1088;
  int kl = r2 / 17;
  int j  = r2 - kl * 17;
  const float dt = 2.0f / 17.0f;
  float cs = 0.f, ss = 0.f;
  for (int ry = 0; ry < 128; ++ry) {
    size_t b = (size_t)(ry * 8 + kx) * 2176 + kl * 34;
    cs += part[b + j];
    ss += part[b + 17 + j];
  }
  const float invB = 1.0f / (float)BB;
  float r  = cs * invB;
  float im = ss * invB;
  float t = dt * (float)(j + 1);
  float wq = (j == 0 || j == TT - 1) ? dt * 0.5f : dt;
  float tcf = expf(-0.5f * t * t);
  float val = wq * (r * r + im * im - 2.0f * r * tcf + tcf * tcf) / (float)KK;

  __shared__ float red[256];
  int tid = threadIdx.x;
  red[tid] = val; __syncthreads();
  for (int s = 128; s > 0; s >>= 1) {
    if (tid < s) red[tid] += red[tid + s];
    __syncthreads();
  }
  if (tid == 0) atomicAdd(out, red[0]);
}

extern "C" void kernel_launch(void* const* d_in, const int* in_sizes, int n_in,
                              void* d_out, int out_size, void* d_ws, size_t ws_size,
                              hipStream_t stream) {
  const float* z   = (const float*)d_in[0];   // (B, D) fp32
  const float* dir = (const float*)d_in[1];   // (D, K) fp32
  float* out = (float*)d_out;

  // workspace layout (bytes)
  uint8_t* w8 = (uint8_t*)d_ws;
  unsigned short* zb = (unsigned short*)w8;                   // 32 MB bf16
  float* part        = (float*)w8;                            // 8.9 MB (ecf partials; reuses zb AFTER gemm)
  unsigned short* dT = (unsigned short*)(w8 + 33554432);      //  2 MB bf16
  float* proj        = (float*)(w8 + 35651584);               // 16 MB fp32
  float* part2       = (float*)(w8 + 35651584);               // 16 MB (z col partials; consumed BEFORE gemm)
  float* stat        = (float*)(w8 + 52428800);
  float* part5    = stat;                  // 8*4096 = 32768 floats (z fold stage 1)
  float* psum     = part5 + 32768;         // KK
  float* psumsq   = psum + KK;             // KK (contiguous after psum)
  float* invnorm  = psumsq + KK;           // KK
  float* part3    = invnorm + KK;          // 32*KK = 16384 floats (dir partials)

  // 1. z -> bf16 + per-block col partials (no atomics), 1024 blocks
  prep_z_kernel<<<dim3(NZB), 256, 0, stream>>>(z, zb, part2);
  // 2. merged fold: z col partials (512 blocks) + dir sumsq (32 blocks)
  reduce2_kernel<<<dim3(544), 256, 0, stream>>>(part2, part5, dir, part3);
  // 3. invnorm + var_floor (seeds out[0]) + zero psum/psumsq
  finalize1_kernel<<<1, 256, 0, stream>>>(part5, part3, invnorm, out, psum);
  // 4. dir -> normalized bf16 transpose (K, D)
  dirT_kernel<<<dim3(8, 32), 256, 0, stream>>>(dir, invnorm, dT);
  // 5. bf16 MFMA GEMM (+fused proj column stats), BK=128
  gemm_bf16_kernel<<<dim3(256), 256, 0, stream>>>(zb, dT, proj, psum, psumsq);
  // 6. ECF partial sums, 1024 blocks (inline mu/invsig)
  ecf_kernel<<<dim3(8, 128), 256, 0, stream>>>(proj, psum, psumsq, part);
  // 7. reduce + integrand + quadrature -> out
  ecf_final_kernel<<<dim3(34), 256, 0, stream>>>(part, out);
}

// Round 16
// 94.641 us; speedup vs baseline: 1.2101x; 1.2101x over previous
//
#include <hip/hip_runtime.h>
#include <hip/hip_bf16.h>

// Problem constants
#define BB   8192      // batch
#define DD   2048      // embed dim
#define KK   512       // num directions
#define TT   17        // quadrature points

// GEMM tile: 128x128x128, 256 blocks (1/CU), 2-phase proven sync, NT=16.
#define BM   128
#define BN   128
#define BK   128
#define NT   (DD / BK)   // 16 K-steps

#define NZB  512         // prep_z row-split blocks (16 rows each)

typedef __attribute__((ext_vector_type(8))) short  bf16x8;
typedef __attribute__((ext_vector_type(4))) float  f32x4;

__device__ __forceinline__ void gload16(const void* g, void* l) {
  __builtin_amdgcn_global_load_lds(
      (const __attribute__((address_space(1))) void*)g,
      (__attribute__((address_space(3))) void*)l,
      16, 0, 0);
}

// ---------- prep z: bf16 conversion + NON-ATOMIC per-block col partials -------
// R13 config: 512 blocks x 16 rows; thread owns 8 contiguous cols.
__global__ __launch_bounds__(256) void prep_z_kernel(
    const float* __restrict__ z, unsigned short* __restrict__ zb,
    float* __restrict__ part2) {
  int c = threadIdx.x * 8;              // 0..2040
  int r0 = blockIdx.x * 16;
  float s[8] = {0,0,0,0,0,0,0,0}, ss[8] = {0,0,0,0,0,0,0,0};
  for (int ch = 0; ch < 4; ++ch) {
    float4 u[4][2];
    #pragma unroll
    for (int rr = 0; rr < 4; ++rr) {
      const float* p = &z[(size_t)(r0 + ch * 4 + rr) * DD + c];
      u[rr][0] = *(const float4*)p;
      u[rr][1] = *(const float4*)(p + 4);
    }
    #pragma unroll
    for (int rr = 0; rr < 4; ++rr) {
      float f[8] = {u[rr][0].x, u[rr][0].y, u[rr][0].z, u[rr][0].w,
                    u[rr][1].x, u[rr][1].y, u[rr][1].z, u[rr][1].w};
      bf16x8 o;
      #pragma unroll
      for (int i = 0; i < 8; ++i) {
        s[i] += f[i]; ss[i] += f[i] * f[i];
        __hip_bfloat16 h = __float2bfloat16(f[i]);
        o[i] = *(short*)&h;
      }
      *(bf16x8*)&zb[(size_t)(r0 + ch * 4 + rr) * DD + c] = o;
    }
  }
  float* pb = part2 + (size_t)blockIdx.x * 4096;
  *(float4*)&pb[c]        = (float4){s[0], s[1], s[2], s[3]};
  *(float4*)&pb[c + 4]    = (float4){s[4], s[5], s[6], s[7]};
  *(float4*)&pb[2048 + c]     = (float4){ss[0], ss[1], ss[2], ss[3]};
  *(float4*)&pb[2048 + c + 4] = (float4){ss[4], ss[5], ss[6], ss[7]};
}

// ---------- merged fold (R13 config: 288 blocks) ------------------------------
__global__ __launch_bounds__(256) void reduce2_kernel(
    const float* __restrict__ part2, float* __restrict__ part5,
    const float* __restrict__ dir, float* __restrict__ part3) {
  int bid = blockIdx.x;
  int tid = threadIdx.x;
  if (bid < 256) {
    int dgrp = bid & 63, bq = bid >> 6;      // d-group 0..63, b-quarter 0..3
    int d = dgrp * 64 + (tid & 63);          // 0..4095 (sum|sumsq columns)
    int ch = tid >> 6;                       // 0..3
    int b0 = bq * 128 + ch * 32;
    float s = 0.f;
    for (int b = b0; b < b0 + 32; ++b)
      s += part2[(size_t)b * 4096 + d];
    __shared__ float rs[4][64];
    rs[ch][tid & 63] = s;
    __syncthreads();
    if (tid < 64)
      part5[(size_t)bq * 4096 + dgrp * 64 + tid] =
          rs[0][tid] + rs[1][tid] + rs[2][tid] + rs[3][tid];
  } else {
    int rg = bid - 256;                      // 0..31, rows [rg*64, +64)
    int c4 = tid & 127;                      // float4 column
    int half = tid >> 7;                     // 0/1 row parity
    int r0 = rg * 64 + half;
    float4 q = {0.f, 0.f, 0.f, 0.f};
    #pragma unroll 8
    for (int i = 0; i < 32; ++i) {
      float4 v = *(const float4*)&dir[(size_t)(r0 + 2 * i) * KK + c4 * 4];
      q.x += v.x * v.x; q.y += v.y * v.y; q.z += v.z * v.z; q.w += v.w * v.w;
    }
    __shared__ float rd[2][512];
    *(float4*)&rd[half][c4 * 4] = q;
    __syncthreads();
    if (tid < 128) {
      float4 a = *(float4*)&rd[0][tid * 4];
      float4 b = *(float4*)&rd[1][tid * 4];
      float4 o = {a.x + b.x, a.y + b.y, a.z + b.z, a.w + b.w};
      *(float4*)&part3[(size_t)rg * KK + tid * 4] = o;
    }
  }
}

// ---------- dirT (blocks 0..255) + var_floor/zero-psum (block 256) ------------
// dirT blocks fold their own 64 invnorms from part3 (4-way LDS fold), then
// normalize + bf16 + transpose. Block 256 does var_floor (seeds out[0]) and
// zeroes psum/psumsq before the GEMM's atomics.
__global__ __launch_bounds__(256) void dirT_kernel(
    const float* __restrict__ dir, const float* __restrict__ part3,
    const float* __restrict__ part5, unsigned short* __restrict__ dT,
    float* __restrict__ out, float* __restrict__ psum) {
  int bid = blockIdx.x;
  int tid = threadIdx.x;
  if (bid < 256) {
    __shared__ unsigned short tile[64][65];   // +1 pad
    __shared__ float fold[4][64];
    __shared__ float sinv[64];
    int n0 = (bid & 7) * 64;    // K dim (8 groups)
    int d0 = (bid >> 3) * 64;   // D dim (32 groups)
    int tx = tid & 63, ty = tid >> 6;
    float ssq = 0.f;
    #pragma unroll
    for (int i = 0; i < 8; ++i)
      ssq += part3[(size_t)(ty * 8 + i) * KK + n0 + tx];
    fold[ty][tx] = ssq;
    __syncthreads();
    if (tid < 64) {
      float t = fold[0][tid] + fold[1][tid] + fold[2][tid] + fold[3][tid];
      sinv[tid] = 1.0f / fmaxf(sqrtf(t), 1e-12f);
    }
    __syncthreads();
    float inv = sinv[tx];
    #pragma unroll
    for (int i = 0; i < 16; ++i) {
      int dr = ty + i * 4;
      float v = dir[(size_t)(d0 + dr) * KK + n0 + tx] * inv;
      __hip_bfloat16 h = __float2bfloat16(v);
      tile[dr][tx] = *(unsigned short*)&h;
    }
    __syncthreads();
    #pragma unroll
    for (int i = 0; i < 16; ++i) {
      int nr = ty + i * 4;
      dT[(size_t)(n0 + nr) * DD + d0 + tx] = tile[tx][nr];
    }
  } else {
    for (int i = tid; i < 2 * KK; i += 256) psum[i] = 0.f;
    float acc = 0.f;
    for (int d = tid; d < DD; d += 256) {
      float s = 0.f, ss = 0.f;
      #pragma unroll
      for (int i = 0; i < 4; ++i) {
        s  += part5[i * 4096 + d];
        ss += part5[i * 4096 + 2048 + d];
      }
      float var = (ss - s * s / (float)BB) / (float)(BB - 1);
      float sd = sqrtf(fmaxf(var, 0.f));
      acc += fmaxf(1.0f - sd, 0.0f);
    }
    __shared__ float red[256];
    red[tid] = acc; __syncthreads();
    for (int s = 128; s > 0; s >>= 1) {
      if (tid < s) red[tid] += red[tid + s];
      __syncthreads();
    }
    if (tid == 0) out[0] = red[0] / (float)DD;   // ecf_final adds the rest
  }
}

// ---------- bf16 MFMA GEMM: projb(B,K bf16) = zb(B,D) @ dT(K,D)^T -------------
// R13-proven loop; epilogue stores bf16 proj + fused fp32 column stats.
__global__ __launch_bounds__(256) void gemm_bf16_kernel(
    const unsigned short* __restrict__ zb, const unsigned short* __restrict__ dT,
    unsigned short* __restrict__ projb, float* __restrict__ psum,
    float* __restrict__ psumsq) {
  __shared__ __align__(16) short As[2][BM * BK];   // 32KB/buf
  __shared__ __align__(16) short Bs[2][BN * BK];   // 32KB/buf

  int tid = threadIdx.x;
  int w = tid >> 6, l = tid & 63;

  // XCD-chunked swizzle (bijective): XCD x owns m-blocks [x*8, x*8+8)
  int bid = blockIdx.x;               // 0..255
  int xcd = bid & 7, slot = bid >> 3; // slot 0..31
  int bmi = xcd * 8 + (slot >> 2);    // 0..63
  int bni = slot & 3;                 // 0..3
  int bm = bmi * BM, bn = bni * BN;

  // Staging: one gload16 covers 4 rows x 16 granules (lane->row l>>4, gran l&15).
  int r4 = l >> 4;                     // row within 4-row gload (0..3)
  int gsw_e = ((l & 15) ^ r4) * 8;     // even strip: row&7 = r4
  int gsw_o = ((l & 15) ^ (r4 + 4)) * 8; // odd strip: row&7 = r4+4
  const unsigned short* aRow = zb + (size_t)(bm + w * 32 + r4) * DD;
  const unsigned short* bRow = dT + (size_t)(bn + w * 32 + r4) * DD;

#define STAGE(buf, kt) do {                                                   \
    const unsigned short* a_ = aRow + (size_t)(kt) * BK;                      \
    const unsigned short* b_ = bRow + (size_t)(kt) * BK;                      \
    gload16(a_ + 0 * 4 * DD + gsw_e, &As[buf][(w * 32 + 0) * BK]);            \
    gload16(b_ + 0 * 4 * DD + gsw_e, &Bs[buf][(w * 32 + 0) * BK]);            \
    gload16(a_ + 1 * 4 * DD + gsw_o, &As[buf][(w * 32 + 4) * BK]);            \
    gload16(b_ + 1 * 4 * DD + gsw_o, &Bs[buf][(w * 32 + 4) * BK]);            \
    gload16(a_ + 2 * 4 * DD + gsw_e, &As[buf][(w * 32 + 8) * BK]);            \
    gload16(b_ + 2 * 4 * DD + gsw_e, &Bs[buf][(w * 32 + 8) * BK]);            \
    gload16(a_ + 3 * 4 * DD + gsw_o, &As[buf][(w * 32 + 12) * BK]);           \
    gload16(b_ + 3 * 4 * DD + gsw_o, &Bs[buf][(w * 32 + 12) * BK]);           \
    gload16(a_ + 4 * 4 * DD + gsw_e, &As[buf][(w * 32 + 16) * BK]);           \
    gload16(b_ + 4 * 4 * DD + gsw_e, &Bs[buf][(w * 32 + 16) * BK]);           \
    gload16(a_ + 5 * 4 * DD + gsw_o, &As[buf][(w * 32 + 20) * BK]);           \
    gload16(b_ + 5 * 4 * DD + gsw_o, &Bs[buf][(w * 32 + 20) * BK]);           \
    gload16(a_ + 6 * 4 * DD + gsw_e, &As[buf][(w * 32 + 24) * BK]);           \
    gload16(b_ + 6 * 4 * DD + gsw_e, &Bs[buf][(w * 32 + 24) * BK]);           \
    gload16(a_ + 7 * 4 * DD + gsw_o, &As[buf][(w * 32 + 28) * BK]);           \
    gload16(b_ + 7 * 4 * DD + gsw_o, &Bs[buf][(w * 32 + 28) * BK]);           \
  } while (0)

  int wm = (w >> 1) * 64, wn = (w & 1) * 64;
  int fr = l & 15, fq = l >> 4;
  int fx = fr & 7;                     // = (LDS row)&7 for all fragment rows

  f32x4 acc[4][4];
  f32x4 zero4 = {0.f, 0.f, 0.f, 0.f};
  #pragma unroll
  for (int mi = 0; mi < 4; ++mi)
    #pragma unroll
    for (int ni = 0; ni < 4; ++ni) acc[mi][ni] = zero4;

  STAGE(0, 0);
  asm volatile("s_waitcnt vmcnt(0)" ::: "memory");
  __builtin_amdgcn_s_barrier();

  for (int t = 0; t < NT; ++t) {
    int cur = t & 1;
    if (t + 1 < NT) STAGE(cur ^ 1, t + 1);   // issue next-tile loads first
    #pragma unroll
    for (int kk = 0; kk < 4; ++kk) {
      bf16x8 av[4], bv[4];
      int go = ((kk * 4 + fq) ^ fx) * 8;     // swizzled 16B-granule read
      #pragma unroll
      for (int mi = 0; mi < 4; ++mi)
        av[mi] = *(const bf16x8*)&As[cur][(wm + mi * 16 + fr) * BK + go];
      #pragma unroll
      for (int ni = 0; ni < 4; ++ni)
        bv[ni] = *(const bf16x8*)&Bs[cur][(wn + ni * 16 + fr) * BK + go];
      #pragma unroll
      for (int mi = 0; mi < 4; ++mi)
        #pragma unroll
        for (int ni = 0; ni < 4; ++ni)
          acc[mi][ni] = __builtin_amdgcn_mfma_f32_16x16x32_bf16(av[mi], bv[ni], acc[mi][ni], 0, 0, 0);
    }
    asm volatile("s_waitcnt vmcnt(0)" ::: "memory");   // next tile staged
    __builtin_amdgcn_s_barrier();                      // + all reads of cur done
  }
#undef STAGE

  // Epilogue: bf16 proj store + fused fp32 column stats (over wave's 64 rows)
  #pragma unroll
  for (int ni = 0; ni < 4; ++ni) {
    float s = 0.f, q = 0.f;
    int col = bn + wn + ni * 16 + fr;
    #pragma unroll
    for (int mi = 0; mi < 4; ++mi)
      #pragma unroll
      for (int j = 0; j < 4; ++j) {
        float v = acc[mi][ni][j];
        s += v; q += v * v;
        __hip_bfloat16 h = __float2bfloat16(v);
        projb[(size_t)(bm + wm + mi * 16 + fq * 4 + j) * KK + col] =
            *(unsigned short*)&h;
      }
    s += __shfl_xor(s, 16); q += __shfl_xor(q, 16);
    s += __shfl_xor(s, 32); q += __shfl_xor(q, 32);
    if (fq == 0) {
      atomicAdd(&psum[col], s);
      atomicAdd(&psumsq[col], q);
    }
  }
}

// ---------- ECF: block (kx,ry) covers 64 k-cols x 128 rows (bf16 proj) --------
__global__ __launch_bounds__(256) void ecf_kernel(
    const unsigned short* __restrict__ projb, const float* __restrict__ psum,
    const float* __restrict__ psumsq, float* __restrict__ part) {
  int kx = blockIdx.x, ry = blockIdx.y;
  int tid = threadIdx.x;
  int kl = tid & 63, w = tid >> 6;
  int k = kx * 64 + kl;
  float sk = psum[k], qk = psumsq[k];
  float m = sk / (float)BB;
  float var = (qk - sk * sk / (float)BB) / (float)(BB - 1);
  float sd = sqrtf(fmaxf(var, 0.f));
  float is = 1.0f / (sd + 1e-8f);
  int r0 = ry * 128 + w * 32;
  const float dt = 2.0f / 17.0f;

  float ac[TT], as[TT];
  #pragma unroll
  for (int j = 0; j < TT; ++j) { ac[j] = 0.f; as[j] = 0.f; }

  #pragma unroll 4
  for (int i = 0; i < 32; ++i) {
    unsigned short u = projb[(size_t)(r0 + i) * KK + k];
    float pv = __bfloat162float(*(const __hip_bfloat16*)&u);
    float p = (pv - m) * is;
    float th = dt * p;
    float s1, c1;
    __sincosf(th, &s1, &c1);
    float tc = 2.0f * c1;
    float cj = c1, sj = s1, cjm = 1.0f, sjm = 0.0f;
    ac[0] += c1; as[0] += s1;
    #pragma unroll
    for (int j = 1; j < TT; ++j) {
      float cn = tc * cj - cjm;
      float sn = tc * sj - sjm;
      cjm = cj; sjm = sj; cj = cn; sj = sn;
      ac[j] += cj; as[j] += sj;
    }
  }

  __shared__ float red[4 * 2176];     // [wave][kl*34 + jj]
  int base = w * 2176 + kl * 34;
  #pragma unroll
  for (int j = 0; j < TT; ++j) {
    red[base + j] = ac[j];
    red[base + 17 + j] = as[j];
  }
  __syncthreads();
  for (int idx = tid; idx < 2176; idx += 256) {
    float v = red[idx] + red[2176 + idx] + red[4352 + idx] + red[6528 + idx];
    part[(size_t)(ry * 8 + kx) * 2176 + idx] = v;
  }
}

// ---------- reduce partials -> integrand -> atomic add into out ---------------
__global__ __launch_bounds__(256) void ecf_final_kernel(
    const float* __restrict__ part, float* __restrict__ out) {
  int gi = blockIdx.x * 256 + threadIdx.x;   // 0..8703 = 512k x 17j
  int kx = gi / 1088;                        // 1088 = 64*17
  int r2 = gi - kx * 1088;
  int kl = r2 / 17;
  int j  = r2 - kl * 17;
  const float dt = 2.0f / 17.0f;
  float cs = 0.f, ss = 0.f;
  for (int ry = 0; ry < 64; ++ry) {
    size_t b = (size_t)(ry * 8 + kx) * 2176 + kl * 34;
    cs += part[b + j];
    ss += part[b + 17 + j];
  }
  const float invB = 1.0f / (float)BB;
  float r  = cs * invB;
  float im = ss * invB;
  float t = dt * (float)(j + 1);
  float wq = (j == 0 || j == TT - 1) ? dt * 0.5f : dt;
  float tcf = expf(-0.5f * t * t);
  float val = wq * (r * r + im * im - 2.0f * r * tcf + tcf * tcf) / (float)KK;

  __shared__ float red[256];
  int tid = threadIdx.x;
  red[tid] = val; __syncthreads();
  for (int s = 128; s > 0; s >>= 1) {
    if (tid < s) red[tid] += red[tid + s];
    __syncthreads();
  }
  if (tid == 0) atomicAdd(out, red[0]);
}

extern "C" void kernel_launch(void* const* d_in, const int* in_sizes, int n_in,
                              void* d_out, int out_size, void* d_ws, size_t ws_size,
                              hipStream_t stream) {
  const float* z   = (const float*)d_in[0];   // (B, D) fp32
  const float* dir = (const float*)d_in[1];   // (D, K) fp32
  float* out = (float*)d_out;

  // workspace layout (bytes)
  uint8_t* w8 = (uint8_t*)d_ws;
  unsigned short* zb    = (unsigned short*)w8;                // 32 MB bf16
  float* part           = (float*)w8;                         // 4.46 MB (ecf partials; reuses zb AFTER gemm)
  unsigned short* dT    = (unsigned short*)(w8 + 33554432);   //  2 MB bf16
  unsigned short* projb = (unsigned short*)(w8 + 35651584);   //  8 MB bf16
  float* part2          = (float*)(w8 + 35651584);            //  8 MB (consumed BEFORE gemm)
  float* stat           = (float*)(w8 + 52428800);
  float* part5    = stat;                  // 4*4096 floats (z fold stage 1)
  float* psum     = part5 + 16384;         // KK
  float* psumsq   = psum + KK;             // KK (contiguous after psum)
  float* part3    = psumsq + KK;           // 32*KK floats (dir partials)

  // 1. z -> bf16 + per-block col partials (no atomics)
  prep_z_kernel<<<dim3(NZB), 256, 0, stream>>>(z, zb, part2);
  // 2. merged fold: z col partials (256 blocks) + dir sumsq (32 blocks)
  reduce2_kernel<<<dim3(288), 256, 0, stream>>>(part2, part5, dir, part3);
  // 3. dirT (inline invnorm fold) + var_floor/zero-psum (block 256)
  dirT_kernel<<<dim3(257), 256, 0, stream>>>(dir, part3, part5, dT, out, psum);
  // 4. bf16 MFMA GEMM -> bf16 proj + fused fp32 column stats
  gemm_bf16_kernel<<<dim3(256), 256, 0, stream>>>(zb, dT, projb, psum, psumsq);
  // 5. ECF partial sums (inline mu/invsig; part overwrites zb region)
  ecf_kernel<<<dim3(8, 64), 256, 0, stream>>>(projb, psum, psumsq, part);
  // 6. reduce + integrand + quadrature -> out
  ecf_final_kernel<<<dim3(34), 256, 0, stream>>>(part, out);
}